// Round 5
// baseline (254.529 us; speedup 1.0000x reference)
//
#include <hip/hip_runtime.h>
#include <math.h>

// SOM2dLayer forward: BMU indices + quantization error via bf16-MFMA screen
// + exact fp32 rescore.
// X[4096,64] f32, W[65536,64] f32 -> out f32: [B*2] (y,x) then [B] qe.
//
// s(row,n) = w2[n] - 2*x.w  (x2 added only for qe). acc' = x.w - w2/2,
// s = -2*acc', so min over s == max over acc'. Phases:
//   prep:    whi = bf16(w), w2c = -0.5*sum(w^2); xhi = bf16(x)
//   screen0: per (panel,row) max of acc'  -> pm
//   reduce:  thr2[row] = max_p pm - MARGIN/2 ; cnt = 0
//   screen1: recompute ONLY waves whose rows have pm >= thr (lossless skip),
//            collect n with acc' >= thr (atomic append)
//   final:   exact fp32 rescore of <=64 candidates/row, argmin with index
//            tie-break (np first-occurrence), qe = sqrt(max(x2+s,0))
//
// Round-5 deltas vs round-4 (which was latency-bound at 1.3 waves/SIMD):
//   - 32 rows/wave (was 128): reg footprint ~70 -> 4+ waves/SIMD
//   - 1-tile prefetch of b0/b1/w2c
//   - XCD-aware block map: one panel's 32 row-blocks share an XCD's L2
//   - screen1 early-exit on pm<thr (exact, not approximate)

typedef short  bf16x8 __attribute__((ext_vector_type(8)));
typedef float  f32x4  __attribute__((ext_vector_type(4)));
typedef unsigned short u16;

constexpr int D        = 64;
constexpr int NW       = 65536;
constexpr int B        = 4096;
constexpr int NPANELS  = 256;        // panels of 256 n
constexpr int CAND_CAP = 64;
constexpr float MARG_HALF = 0.15f;   // margin 0.3 in distance space

__device__ inline u16 bf16u(float f) {
    union { float f; unsigned u; } v; v.f = f;
    unsigned b = v.u;
    b += 0x7fffu + ((b >> 16) & 1u);   // RNE, finite inputs only
    return (u16)(b >> 16);
}

// ---- prep: W -> bf16 + w2c ------------------------------------------------
__global__ __launch_bounds__(256) void k_wprep(const float* __restrict__ w,
                                               u16* __restrict__ whi,
                                               float* __restrict__ w2c) {
    int n = blockIdx.x * 256 + threadIdx.x;
    const float4* wr = reinterpret_cast<const float4*>(w + (size_t)n * D);
    u16* orow = whi + (size_t)n * D;
    float a0 = 0.f, a1 = 0.f, a2 = 0.f, a3 = 0.f;
#pragma unroll
    for (int h = 0; h < 8; ++h) {
        float4 v0 = wr[2 * h], v1 = wr[2 * h + 1];
        a0 = fmaf(v0.x, v0.x, a0); a1 = fmaf(v0.y, v0.y, a1);
        a2 = fmaf(v0.z, v0.z, a2); a3 = fmaf(v0.w, v0.w, a3);
        a0 = fmaf(v1.x, v1.x, a0); a1 = fmaf(v1.y, v1.y, a1);
        a2 = fmaf(v1.z, v1.z, a2); a3 = fmaf(v1.w, v1.w, a3);
        bf16x8 o = {(short)bf16u(v0.x), (short)bf16u(v0.y),
                    (short)bf16u(v0.z), (short)bf16u(v0.w),
                    (short)bf16u(v1.x), (short)bf16u(v1.y),
                    (short)bf16u(v1.z), (short)bf16u(v1.w)};
        *reinterpret_cast<bf16x8*>(orow + 8 * h) = o;
    }
    w2c[n] = -0.5f * ((a0 + a1) + (a2 + a3));
}

__global__ __launch_bounds__(256) void k_xprep(const float* __restrict__ x,
                                               u16* __restrict__ xhi) {
    int r = blockIdx.x * 256 + threadIdx.x;
    const float4* xr = reinterpret_cast<const float4*>(x + (size_t)r * D);
    u16* orow = xhi + (size_t)r * D;
#pragma unroll
    for (int h = 0; h < 8; ++h) {
        float4 v0 = xr[2 * h], v1 = xr[2 * h + 1];
        bf16x8 o = {(short)bf16u(v0.x), (short)bf16u(v0.y),
                    (short)bf16u(v0.z), (short)bf16u(v0.w),
                    (short)bf16u(v1.x), (short)bf16u(v1.y),
                    (short)bf16u(v1.z), (short)bf16u(v1.w)};
        *reinterpret_cast<bf16x8*>(orow + 8 * h) = o;
    }
}

// ---- MFMA screen ----------------------------------------------------------
// Wave: 32 rows (2 groups of 16) x 256-n panel (16 tiles of 16 n).
// Block: 4 waves = 128 rows. Grid: 32 row-blocks x 256 panels = 8192 blocks.
// XCD map: panel p handled only by blocks with bid%8 == p%8 -> panel whi
// (32 KB) stays in one XCD's L2.
template <int PHASE>
__global__ __launch_bounds__(256, 4) void k_screen(const u16* __restrict__ whi,
                                                   const u16* __restrict__ xhi,
                                                   const float* __restrict__ w2c,
                                                   float* __restrict__ pm,
                                                   const float* __restrict__ thr2,
                                                   int* __restrict__ cnt,
                                                   int* __restrict__ cand) {
    const int bid  = blockIdx.x;
    const int xcd  = bid & 7;
    const int idx  = bid >> 3;          // 0..1023
    const int p    = (idx >> 5) * 8 + xcd;   // panel 0..255
    const int rbk  = idx & 31;               // row-block 0..31
    const int wave = threadIdx.x >> 6;
    const int lane = threadIdx.x & 63;
    const int col  = lane & 15;         // MFMA lane col
    const int kg   = lane >> 4;         // k-group 0..3
    const int row0 = rbk * 128 + wave * 32;
    const int p0   = p * 256;

    float t0[4], t1[4];   // PHASE 1 thresholds
    if (PHASE == 1) {
        // lossless early-exit: no row of this wave has a candidate in panel p
        float pmv = -3.4e38f, th = 0.f;
        if (lane < 32) {
            pmv = pm[(size_t)p * B + row0 + lane];
            th  = thr2[row0 + lane];
        }
        if (!__any(pmv >= th)) return;
#pragma unroll
        for (int r = 0; r < 4; ++r) {
            t0[r] = thr2[row0 + kg * 4 + r];
            t1[r] = thr2[row0 + 16 + kg * 4 + r];
        }
    }

    // A fragments: 2 row-groups x 2 k-halves, 16B contiguous each.
    bf16x8 a00 = *reinterpret_cast<const bf16x8*>(xhi + (size_t)(row0 + col) * D + kg * 8);
    bf16x8 a01 = *reinterpret_cast<const bf16x8*>(xhi + (size_t)(row0 + col) * D + 32 + kg * 8);
    bf16x8 a10 = *reinterpret_cast<const bf16x8*>(xhi + (size_t)(row0 + 16 + col) * D + kg * 8);
    bf16x8 a11 = *reinterpret_cast<const bf16x8*>(xhi + (size_t)(row0 + 16 + col) * D + 32 + kg * 8);

    float m0[4], m1[4];
    if (PHASE == 0) {
#pragma unroll
        for (int r = 0; r < 4; ++r) { m0[r] = -3.4e38f; m1[r] = -3.4e38f; }
    }

    // lane-fixed base for B fragments; tile steps by 16 rows * 64 u16 = 1024
    const u16* wl = whi + (size_t)(p0 + col) * D + kg * 8;

    bf16x8 nb0 = *reinterpret_cast<const bf16x8*>(wl);
    bf16x8 nb1 = *reinterpret_cast<const bf16x8*>(wl + 32);
    float  ncv = w2c[p0 + col];

#pragma unroll
    for (int tl = 0; tl < 16; ++tl) {
        bf16x8 b0 = nb0, b1 = nb1;
        float  c  = ncv;
        if (tl < 15) {
            nb0 = *reinterpret_cast<const bf16x8*>(wl + (tl + 1) * 1024);
            nb1 = *reinterpret_cast<const bf16x8*>(wl + (tl + 1) * 1024 + 32);
            ncv = w2c[p0 + (tl + 1) * 16 + col];
        }
        f32x4 acc0 = {c, c, c, c};
        f32x4 acc1 = {c, c, c, c};
        acc0 = __builtin_amdgcn_mfma_f32_16x16x32_bf16(a00, b0, acc0, 0, 0, 0);
        acc1 = __builtin_amdgcn_mfma_f32_16x16x32_bf16(a10, b0, acc1, 0, 0, 0);
        acc0 = __builtin_amdgcn_mfma_f32_16x16x32_bf16(a01, b1, acc0, 0, 0, 0);
        acc1 = __builtin_amdgcn_mfma_f32_16x16x32_bf16(a11, b1, acc1, 0, 0, 0);

        if (PHASE == 0) {
#pragma unroll
            for (int r = 0; r < 4; ++r) {
                m0[r] = fmaxf(m0[r], acc0[r]);
                m1[r] = fmaxf(m1[r], acc1[r]);
            }
        } else {
            float dm = fmaxf(fmaxf(fmaxf(acc0[0] - t0[0], acc0[1] - t0[1]),
                                   fmaxf(acc0[2] - t0[2], acc0[3] - t0[3])),
                             fmaxf(fmaxf(acc1[0] - t1[0], acc1[1] - t1[1]),
                                   fmaxf(acc1[2] - t1[2], acc1[3] - t1[3])));
            if (__any(dm >= 0.f)) {   // rare slow path
                const int n = p0 + tl * 16 + col;
#pragma unroll
                for (int r = 0; r < 4; ++r) {
                    if (acc0[r] >= t0[r]) {
                        int row  = row0 + kg * 4 + r;
                        int slot = atomicAdd(&cnt[row], 1);
                        if (slot < CAND_CAP) cand[row * CAND_CAP + slot] = n;
                    }
                    if (acc1[r] >= t1[r]) {
                        int row  = row0 + 16 + kg * 4 + r;
                        int slot = atomicAdd(&cnt[row], 1);
                        if (slot < CAND_CAP) cand[row * CAND_CAP + slot] = n;
                    }
                }
            }
        }
    }

    if (PHASE == 0) {
        // fold 16 cols (lanes sharing kg) -> per-row panel max
#pragma unroll
        for (int r = 0; r < 4; ++r) {
            float v = m0[r];
            v = fmaxf(v, __shfl_xor(v, 1, 64));
            v = fmaxf(v, __shfl_xor(v, 2, 64));
            v = fmaxf(v, __shfl_xor(v, 4, 64));
            v = fmaxf(v, __shfl_xor(v, 8, 64));
            m0[r] = v;
            float u = m1[r];
            u = fmaxf(u, __shfl_xor(u, 1, 64));
            u = fmaxf(u, __shfl_xor(u, 2, 64));
            u = fmaxf(u, __shfl_xor(u, 4, 64));
            u = fmaxf(u, __shfl_xor(u, 8, 64));
            m1[r] = u;
        }
        if (col == 0) {
#pragma unroll
            for (int r = 0; r < 4; ++r) {
                pm[(size_t)p * B + row0 + kg * 4 + r]      = m0[r];
                pm[(size_t)p * B + row0 + 16 + kg * 4 + r] = m1[r];
            }
        }
    }
}

// ---- reduce panel maxima -> threshold; zero candidate counters ------------
__global__ __launch_bounds__(256) void k_reduce(const float* __restrict__ pm,
                                                float* __restrict__ thr2,
                                                int* __restrict__ cnt) {
    int row = blockIdx.x * 256 + threadIdx.x;
    float gm = -3.4e38f;
    for (int p = 0; p < NPANELS; ++p) gm = fmaxf(gm, pm[(size_t)p * B + row]);
    thr2[row] = gm - MARG_HALF;
    cnt[row] = 0;
}

// ---- exact fp32 rescore + output ------------------------------------------
__global__ __launch_bounds__(256) void k_final(const float* __restrict__ x,
                                               const float* __restrict__ w,
                                               const float* __restrict__ w2c,
                                               const int* __restrict__ cnt,
                                               const int* __restrict__ cand,
                                               float* __restrict__ out) {
    int row  = blockIdx.x * 4 + (threadIdx.x >> 6);
    int lane = threadIdx.x & 63;
    int c = cnt[row]; c = c < CAND_CAP ? c : CAND_CAP;
    float val = 3.4e38f;
    int   ni  = 0x7fffffff;
    if (lane < c) {
        int n = cand[row * CAND_CAP + lane];
        const float4* wr = reinterpret_cast<const float4*>(w + (size_t)n * D);
        const float4* xr = reinterpret_cast<const float4*>(x + (size_t)row * D);
        float d0 = 0.f, d1 = 0.f, d2 = 0.f, d3 = 0.f;
#pragma unroll
        for (int q = 0; q < 16; ++q) {
            float4 wv = wr[q];
            float4 xv = xr[q];
            d0 = fmaf(xv.x, wv.x, d0); d1 = fmaf(xv.y, wv.y, d1);
            d2 = fmaf(xv.z, wv.z, d2); d3 = fmaf(xv.w, wv.w, d3);
        }
        float dot = (d0 + d1) + (d2 + d3);
        val = -2.f * (dot + w2c[n]);      // == w2 - 2*x.w
        ni  = n;
    }
#pragma unroll
    for (int s = 1; s < 64; s <<= 1) {
        float ov = __shfl_xor(val, s, 64);
        int   oi = __shfl_xor(ni, s, 64);
        if (ov < val || (ov == val && oi < ni)) { val = ov; ni = oi; }
    }
    if (lane == 0) {
        const float4* xr = reinterpret_cast<const float4*>(x + (size_t)row * D);
        float a0 = 0.f, a1 = 0.f, a2 = 0.f, a3 = 0.f;
#pragma unroll
        for (int q = 0; q < 16; ++q) {
            float4 v = xr[q];
            a0 = fmaf(v.x, v.x, a0); a1 = fmaf(v.y, v.y, a1);
            a2 = fmaf(v.z, v.z, a2); a3 = fmaf(v.w, v.w, a3);
        }
        float x2 = (a0 + a1) + (a2 + a3);
        float d2f = x2 + val;
        if (d2f < 0.f) d2f = 0.f;
        out[row * 2 + 0] = (float)(ni >> 8);    // bmu_y
        out[row * 2 + 1] = (float)(ni & 255);   // bmu_x
        out[2 * B + row] = sqrtf(d2f);
    }
}

// ---- fallback (round-3 proven path, needs only ~1.3 MB ws) ----------------
__global__ __launch_bounds__(256) void fb_w2(const float* __restrict__ w,
                                             float* __restrict__ w2) {
    int n = blockIdx.x * 256 + threadIdx.x;
    const float4* wr = reinterpret_cast<const float4*>(w + (size_t)n * D);
    float a0 = 0.f, a1 = 0.f, a2 = 0.f, a3 = 0.f;
#pragma unroll
    for (int q = 0; q < 16; ++q) {
        float4 v = wr[q];
        a0 = fmaf(v.x, v.x, a0); a1 = fmaf(v.y, v.y, a1);
        a2 = fmaf(v.z, v.z, a2); a3 = fmaf(v.w, v.w, a3);
    }
    w2[n] = (a0 + a1) + (a2 + a3);
}

__global__ __launch_bounds__(256) void fb_main(const float* __restrict__ x,
                                               const float* __restrict__ w,
                                               const float* __restrict__ w2,
                                               float* __restrict__ ps,
                                               int* __restrict__ pi) {
    constexpr int NSTRIP = NW / 32;
    const int rb    = blockIdx.x & 15;
    const int strip = blockIdx.x >> 4;
    const int row   = rb * 256 + threadIdx.x;
    float xr[D];
    const float4* xrow = reinterpret_cast<const float4*>(x + (size_t)row * D);
#pragma unroll
    for (int q = 0; q < 16; ++q) {
        float4 v = xrow[q];
        xr[q * 4 + 0] = v.x; xr[q * 4 + 1] = v.y;
        xr[q * 4 + 2] = v.z; xr[q * 4 + 3] = v.w;
    }
    float best = 3.4e38f; int bidx = 0;
    const int n0 = strip * NSTRIP, n1 = n0 + NSTRIP;
    for (int n = n0; n < n1; ++n) {
        const float* wr = w + (size_t)n * D;
        float a0 = 0.f, a1 = 0.f, a2 = 0.f, a3 = 0.f;
#pragma unroll
        for (int d = 0; d < D; d += 4) {
            a0 = fmaf(xr[d + 0], wr[d + 0], a0);
            a1 = fmaf(xr[d + 1], wr[d + 1], a1);
            a2 = fmaf(xr[d + 2], wr[d + 2], a2);
            a3 = fmaf(xr[d + 3], wr[d + 3], a3);
        }
        float s = fmaf(-2.f, (a0 + a1) + (a2 + a3), w2[n]);
        if (s < best) { best = s; bidx = n; }
    }
    ps[(size_t)strip * B + row] = best;
    pi[(size_t)strip * B + row] = bidx;
}

__global__ __launch_bounds__(256) void fb_merge(const float* __restrict__ x,
                                                const float* __restrict__ ps,
                                                const int* __restrict__ pi,
                                                float* __restrict__ out) {
    int row = blockIdx.x * 256 + threadIdx.x;
    float bs = 3.5e38f; int bi = 0;
    for (int t = 0; t < 32; ++t) {
        float s = ps[(size_t)t * B + row];
        int   i = pi[(size_t)t * B + row];
        if (s < bs || (s == bs && i < bi)) { bs = s; bi = i; }
    }
    const float4* xrow = reinterpret_cast<const float4*>(x + (size_t)row * D);
    float a0 = 0.f, a1 = 0.f, a2 = 0.f, a3 = 0.f;
#pragma unroll
    for (int q = 0; q < 16; ++q) {
        float4 v = xrow[q];
        a0 = fmaf(v.x, v.x, a0); a1 = fmaf(v.y, v.y, a1);
        a2 = fmaf(v.z, v.z, a2); a3 = fmaf(v.w, v.w, a3);
    }
    float x2 = (a0 + a1) + (a2 + a3);
    float d2 = x2 + bs;
    if (d2 < 0.f) d2 = 0.f;
    out[row * 2 + 0] = (float)(bi >> 8);
    out[row * 2 + 1] = (float)(bi & 255);
    out[2 * B + row] = sqrtf(d2);
}

// ---------------------------------------------------------------------------
extern "C" void kernel_launch(void* const* d_in, const int* in_sizes, int n_in,
                              void* d_out, int out_size, void* d_ws, size_t ws_size,
                              hipStream_t stream) {
    const float* x = (const float*)d_in[0];   // [B, D]
    const float* w = (const float*)d_in[1];   // [NW, D]
    float* out = (float*)d_out;

    const size_t whi_sz  = (size_t)NW * D * 2;
    const size_t xhi_sz  = (size_t)B * D * 2;
    const size_t w2c_sz  = (size_t)NW * 4;
    const size_t pm_sz   = (size_t)NPANELS * B * 4;
    const size_t thr_sz  = (size_t)B * 4;
    const size_t cnt_sz  = (size_t)B * 4;
    const size_t cand_sz = (size_t)B * CAND_CAP * 4;
    const size_t need = whi_sz + xhi_sz + w2c_sz + pm_sz + thr_sz + cnt_sz + cand_sz;

    if (ws_size >= need) {
        char* p = (char*)d_ws;
        u16*   whi  = (u16*)p;            p += whi_sz;
        u16*   xhi  = (u16*)p;            p += xhi_sz;
        float* w2c  = (float*)p;          p += w2c_sz;
        float* pm   = (float*)p;          p += pm_sz;
        float* thr2 = (float*)p;          p += thr_sz;
        int*   cnt  = (int*)p;            p += cnt_sz;
        int*   cand = (int*)p;

        k_wprep<<<NW / 256, 256, 0, stream>>>(w, whi, w2c);
        k_xprep<<<B / 256, 256, 0, stream>>>(x, xhi);
        k_screen<0><<<8192, 256, 0, stream>>>(whi, xhi, w2c, pm, thr2, cnt, cand);
        k_reduce<<<B / 256, 256, 0, stream>>>(pm, thr2, cnt);
        k_screen<1><<<8192, 256, 0, stream>>>(whi, xhi, w2c, pm, thr2, cnt, cand);
        k_final<<<B / 4, 256, 0, stream>>>(x, w, w2c, cnt, cand, out);
    } else {
        float* w2 = (float*)d_ws;
        float* ps = w2 + NW;
        int*   pi = (int*)(ps + (size_t)32 * B);
        fb_w2<<<NW / 256, 256, 0, stream>>>(w, w2);
        fb_main<<<16 * 32, 256, 0, stream>>>(x, w, w2, ps, pi);
        fb_merge<<<B / 256, 256, 0, stream>>>(x, ps, pi, out);
    }
}

// Round 6
// 194.252 us; speedup vs baseline: 1.3103x; 1.3103x over previous
//
#include <hip/hip_runtime.h>
#include <math.h>

// SOM2dLayer forward: BMU indices + quantization error.
// X[4096,64] f32, W[65536,64] f32 -> out f32: [B*2] (y,x) then [B] qe.
//
// acc'(row,n) = bf16dot(x,w) + w2c[n], w2c = -0.5*sum(w^2); s = -2*acc'.
// min_n s  <=>  max_n acc'.
//   k_wprep/k_xprep: fp32 -> bf16 copies + exact w2c
//   k_screen0: LDS-staged bf16 MFMA GEMM; per (row, 64n-subchunk) max -> pm
//   k_rescore: per row: thr = max(pm) - MARG; exact fp32 rescore of all n in
//              qualifying subchunks; argmin w/ first-index tie-break; output.
// No atomics anywhere -> deterministic under graph replay.

typedef short  bf16x8 __attribute__((ext_vector_type(8)));
typedef float  f32x4  __attribute__((ext_vector_type(4)));
typedef unsigned short u16;

constexpr int D    = 64;
constexpr int NW   = 65536;
constexpr int B    = 4096;
constexpr int NSUB = 256;              // pm sub-chunks per row (64 n each, scattered)
constexpr float MARG_HALF = 0.15f;     // bf16 screen margin (acc' scale)

// screen geometry
constexpr int STRIPS   = 16;
constexpr int STRIP_N  = NW / STRIPS;  // 4096 n per strip = 16 panels of 256
constexpr int ROWS_BLK = 128;

__device__ inline u16 bf16u(float f) {
    union { float f; unsigned u; } v; v.f = f;
    unsigned b = v.u;
    b += 0x7fffu + ((b >> 16) & 1u);   // RNE, finite inputs only
    return (u16)(b >> 16);
}

__device__ __forceinline__ void gload_lds16(const void* g, void* l) {
    __builtin_amdgcn_global_load_lds(
        (const __attribute__((address_space(1))) unsigned int*)g,
        (__attribute__((address_space(3))) unsigned int*)l, 16, 0, 0);
}

// ---- prep: W -> bf16 + w2c ------------------------------------------------
__global__ __launch_bounds__(256) void k_wprep(const float* __restrict__ w,
                                               u16* __restrict__ whi,
                                               float* __restrict__ w2c) {
    int n = blockIdx.x * 256 + threadIdx.x;
    const float4* wr = reinterpret_cast<const float4*>(w + (size_t)n * D);
    u16* orow = whi + (size_t)n * D;
    float a0 = 0.f, a1 = 0.f, a2 = 0.f, a3 = 0.f;
#pragma unroll
    for (int h = 0; h < 8; ++h) {
        float4 v0 = wr[2 * h], v1 = wr[2 * h + 1];
        a0 = fmaf(v0.x, v0.x, a0); a1 = fmaf(v0.y, v0.y, a1);
        a2 = fmaf(v0.z, v0.z, a2); a3 = fmaf(v0.w, v0.w, a3);
        a0 = fmaf(v1.x, v1.x, a0); a1 = fmaf(v1.y, v1.y, a1);
        a2 = fmaf(v1.z, v1.z, a2); a3 = fmaf(v1.w, v1.w, a3);
        bf16x8 o = {(short)bf16u(v0.x), (short)bf16u(v0.y),
                    (short)bf16u(v0.z), (short)bf16u(v0.w),
                    (short)bf16u(v1.x), (short)bf16u(v1.y),
                    (short)bf16u(v1.z), (short)bf16u(v1.w)};
        *reinterpret_cast<bf16x8*>(orow + 8 * h) = o;
    }
    w2c[n] = -0.5f * ((a0 + a1) + (a2 + a3));
}

__global__ __launch_bounds__(256) void k_xprep(const float* __restrict__ x,
                                               u16* __restrict__ xhi) {
    int r = blockIdx.x * 256 + threadIdx.x;
    const float4* xr = reinterpret_cast<const float4*>(x + (size_t)r * D);
    u16* orow = xhi + (size_t)r * D;
#pragma unroll
    for (int h = 0; h < 8; ++h) {
        float4 v0 = xr[2 * h], v1 = xr[2 * h + 1];
        bf16x8 o = {(short)bf16u(v0.x), (short)bf16u(v0.y),
                    (short)bf16u(v0.z), (short)bf16u(v0.w),
                    (short)bf16u(v1.x), (short)bf16u(v1.y),
                    (short)bf16u(v1.z), (short)bf16u(v1.w)};
        *reinterpret_cast<bf16x8*>(orow + 8 * h) = o;
    }
}

// ---- MFMA screen: LDS-staged, double-buffered -----------------------------
// Block: 4 waves, 128 rows, sweeps one 4096-n strip (16 panels of 256 n).
// Wave wv computes n-range [wv*64, wv*64+64) of each panel.
// LDS: 2 x 32KB W panel slices, XOR-swizzled via pre-swizzled global source.
// pm[row][sub]: sub = strip*16 + chunk*4 + wv, chunk = 4 panels (wave's 256 n).
__global__ __launch_bounds__(256, 2) void k_screen0(
        const u16* __restrict__ whi, const u16* __restrict__ xhi,
        const float* __restrict__ w2c, float* __restrict__ pm) {
    __shared__ __align__(16) char smem[2][32768];
    const int bid   = blockIdx.x;
    const int strip = bid & 15;          // strip -> XCD = strip%8 (L2 colocate)
    const int rbk   = bid >> 4;
    const int tid   = threadIdx.x;
    const int wv    = tid >> 6;
    const int lane  = tid & 63;
    const int col   = lane & 15;
    const int kg    = lane >> 4;
    const int row0  = rbk * ROWS_BLK;

    // A fragments: 8 row-groups x 2 k-halves, resident all kernel (64 VGPR).
    bf16x8 a[8][2];
#pragma unroll
    for (int rg = 0; rg < 8; ++rg)
#pragma unroll
        for (int h = 0; h < 2; ++h)
            a[rg][h] = *reinterpret_cast<const bf16x8*>(
                xhi + (size_t)(row0 + rg * 16 + col) * D + h * 32 + kg * 8);

    // Stage source offsets: LDS linear o <- global (o ^ ((o>>7 &7)<<4)).
    const char* wbase = (const char*)whi + (size_t)strip * STRIP_N * (D * 2);
    unsigned srcoff[8];
#pragma unroll
    for (int i = 0; i < 8; ++i) {
        unsigned o = (unsigned)(i * 256 + tid) * 16;
        srcoff[i] = o ^ (((o >> 7) & 7u) << 4);
    }

    const unsigned msk = (unsigned)(col & 7) << 4;   // read-side swizzle
    const float* w2s = w2c + strip * STRIP_N;

    float mx[8][4];
#pragma unroll
    for (int rg = 0; rg < 8; ++rg)
#pragma unroll
        for (int r = 0; r < 4; ++r) mx[rg][r] = -3.4e38f;

    auto STAGE = [&](int bf, int panel) {
#pragma unroll
        for (int i = 0; i < 8; ++i)
            gload_lds16(wbase + (size_t)panel * 32768 + srcoff[i],
                        &smem[bf][i * 4096 + wv * 1024]);
    };

    STAGE(0, 0);
    __syncthreads();

    for (int p = 0; p < 16; ++p) {
        if (p < 15) STAGE((p + 1) & 1, p + 1);

        const char* buf = smem[p & 1];
        const float* w2p = w2s + p * 256;
#pragma unroll
        for (int t = 0; t < 4; ++t) {
            const int nloc = wv * 64 + t * 16 + col;
            const unsigned u0 = (unsigned)nloc * 128 + kg * 16;
            const bf16x8 b0 = *reinterpret_cast<const bf16x8*>(buf + (u0 ^ msk));
            const bf16x8 b1 = *reinterpret_cast<const bf16x8*>(buf + ((u0 + 64) ^ msk));
            const float c = w2p[nloc];
#pragma unroll
            for (int rg = 0; rg < 8; ++rg) {
                f32x4 acc = {c, c, c, c};
                acc = __builtin_amdgcn_mfma_f32_16x16x32_bf16(a[rg][0], b0, acc, 0, 0, 0);
                acc = __builtin_amdgcn_mfma_f32_16x16x32_bf16(a[rg][1], b1, acc, 0, 0, 0);
                mx[rg][0] = fmaxf(mx[rg][0], acc[0]);
                mx[rg][1] = fmaxf(mx[rg][1], acc[1]);
                mx[rg][2] = fmaxf(mx[rg][2], acc[2]);
                mx[rg][3] = fmaxf(mx[rg][3], acc[3]);
            }
        }

        if ((p & 3) == 3) {   // chunk boundary: fold cols, store pm, reset
            const int chunk = p >> 2;
            const int sub = strip * 16 + chunk * 4 + wv;
#pragma unroll
            for (int rg = 0; rg < 8; ++rg) {
                float v0 = mx[rg][0], v1 = mx[rg][1], v2 = mx[rg][2], v3 = mx[rg][3];
#pragma unroll
                for (int s = 1; s < 16; s <<= 1) {
                    v0 = fmaxf(v0, __shfl_xor(v0, s, 64));
                    v1 = fmaxf(v1, __shfl_xor(v1, s, 64));
                    v2 = fmaxf(v2, __shfl_xor(v2, s, 64));
                    v3 = fmaxf(v3, __shfl_xor(v3, s, 64));
                }
                float vv = v0;
                vv = (col == 1) ? v1 : vv;
                vv = (col == 2) ? v2 : vv;
                vv = (col == 3) ? v3 : vv;
                if (col < 4)
                    pm[(size_t)(row0 + rg * 16 + kg * 4 + col) * NSUB + sub] = vv;
                mx[rg][0] = -3.4e38f; mx[rg][1] = -3.4e38f;
                mx[rg][2] = -3.4e38f; mx[rg][3] = -3.4e38f;
            }
        }
        __syncthreads();
    }
}

// ---- exact fp32 rescore + output (one wave per row) -----------------------
__global__ __launch_bounds__(256) void k_rescore(
        const float* __restrict__ x, const float* __restrict__ w,
        const float* __restrict__ w2c, const float* __restrict__ pm,
        float* __restrict__ out) {
    const int wv   = threadIdx.x >> 6;
    const int lane = threadIdx.x & 63;
    const int row  = blockIdx.x * 4 + wv;

    float pv[4];
#pragma unroll
    for (int it = 0; it < 4; ++it)
        pv[it] = pm[(size_t)row * NSUB + it * 64 + lane];
    float gm = fmaxf(fmaxf(pv[0], pv[1]), fmaxf(pv[2], pv[3]));
#pragma unroll
    for (int s = 1; s < 64; s <<= 1) gm = fmaxf(gm, __shfl_xor(gm, s, 64));
    const float thr = gm - MARG_HALF;

    const float4* xr = reinterpret_cast<const float4*>(x + (size_t)row * D);
    float4 xq[16];
#pragma unroll
    for (int q = 0; q < 16; ++q) xq[q] = xr[q];   // row uniform -> s_load

    float bestv = 3.4e38f;
    int   besti = 0x7fffffff;

#pragma unroll
    for (int it = 0; it < 4; ++it) {
        unsigned long long bm = __ballot(pv[it] >= thr);
        while (bm) {
            int sb = __ffsll(bm) - 1;
            bm &= bm - 1;
            int sub = it * 64 + sb;
            int strip = sub >> 4, chunk = (sub >> 2) & 3, wvv = sub & 3;
            int nb = strip * 4096 + chunk * 1024 + wvv * 64 + lane;
#pragma unroll
            for (int q4 = 0; q4 < 4; ++q4) {
                int n = nb + q4 * 256;
                const float4* wr = reinterpret_cast<const float4*>(w + (size_t)n * D);
                float d0 = 0.f, d1 = 0.f, d2 = 0.f, d3 = 0.f;
#pragma unroll
                for (int q = 0; q < 16; ++q) {
                    float4 wq = wr[q];
                    d0 = fmaf(xq[q].x, wq.x, d0);
                    d1 = fmaf(xq[q].y, wq.y, d1);
                    d2 = fmaf(xq[q].z, wq.z, d2);
                    d3 = fmaf(xq[q].w, wq.w, d3);
                }
                float dot = (d0 + d1) + (d2 + d3);
                float val = -2.f * (dot + w2c[n]);   // == w2 - 2*x.w exact fp32
                if (val < bestv || (val == bestv && n < besti)) { bestv = val; besti = n; }
            }
        }
    }
#pragma unroll
    for (int s = 1; s < 64; s <<= 1) {
        float ov = __shfl_xor(bestv, s, 64);
        int   oi = __shfl_xor(besti, s, 64);
        if (ov < bestv || (ov == bestv && oi < besti)) { bestv = ov; besti = oi; }
    }
    if (lane == 0) {
        float a0 = 0.f, a1 = 0.f, a2 = 0.f, a3 = 0.f;
#pragma unroll
        for (int q = 0; q < 16; ++q) {
            a0 = fmaf(xq[q].x, xq[q].x, a0);
            a1 = fmaf(xq[q].y, xq[q].y, a1);
            a2 = fmaf(xq[q].z, xq[q].z, a2);
            a3 = fmaf(xq[q].w, xq[q].w, a3);
        }
        float x2 = (a0 + a1) + (a2 + a3);
        float d2f = x2 + bestv;
        if (d2f < 0.f) d2f = 0.f;
        out[row * 2 + 0] = (float)(besti >> 8);    // bmu_y
        out[row * 2 + 1] = (float)(besti & 255);   // bmu_x
        out[2 * B + row] = sqrtf(d2f);
    }
}

// ---- fallback (round-3 proven path, ~1.3 MB ws) ---------------------------
__global__ __launch_bounds__(256) void fb_w2(const float* __restrict__ w,
                                             float* __restrict__ w2) {
    int n = blockIdx.x * 256 + threadIdx.x;
    const float4* wr = reinterpret_cast<const float4*>(w + (size_t)n * D);
    float a0 = 0.f, a1 = 0.f, a2 = 0.f, a3 = 0.f;
#pragma unroll
    for (int q = 0; q < 16; ++q) {
        float4 v = wr[q];
        a0 = fmaf(v.x, v.x, a0); a1 = fmaf(v.y, v.y, a1);
        a2 = fmaf(v.z, v.z, a2); a3 = fmaf(v.w, v.w, a3);
    }
    w2[n] = (a0 + a1) + (a2 + a3);
}

__global__ __launch_bounds__(256) void fb_main(const float* __restrict__ x,
                                               const float* __restrict__ w,
                                               const float* __restrict__ w2,
                                               float* __restrict__ ps,
                                               int* __restrict__ pi) {
    constexpr int NSTRIP = NW / 32;
    const int rb    = blockIdx.x & 15;
    const int strip = blockIdx.x >> 4;
    const int row   = rb * 256 + threadIdx.x;
    float xr[D];
    const float4* xrow = reinterpret_cast<const float4*>(x + (size_t)row * D);
#pragma unroll
    for (int q = 0; q < 16; ++q) {
        float4 v = xrow[q];
        xr[q * 4 + 0] = v.x; xr[q * 4 + 1] = v.y;
        xr[q * 4 + 2] = v.z; xr[q * 4 + 3] = v.w;
    }
    float best = 3.4e38f; int bidx = 0;
    const int n0 = strip * NSTRIP, n1 = n0 + NSTRIP;
    for (int n = n0; n < n1; ++n) {
        const float* wr = w + (size_t)n * D;
        float a0 = 0.f, a1 = 0.f, a2 = 0.f, a3 = 0.f;
#pragma unroll
        for (int d = 0; d < D; d += 4) {
            a0 = fmaf(xr[d + 0], wr[d + 0], a0);
            a1 = fmaf(xr[d + 1], wr[d + 1], a1);
            a2 = fmaf(xr[d + 2], wr[d + 2], a2);
            a3 = fmaf(xr[d + 3], wr[d + 3], a3);
        }
        float s = fmaf(-2.f, (a0 + a1) + (a2 + a3), w2[n]);
        if (s < best) { best = s; bidx = n; }
    }
    ps[(size_t)strip * B + row] = best;
    pi[(size_t)strip * B + row] = bidx;
}

__global__ __launch_bounds__(256) void fb_merge(const float* __restrict__ x,
                                                const float* __restrict__ ps,
                                                const int* __restrict__ pi,
                                                float* __restrict__ out) {
    int row = blockIdx.x * 256 + threadIdx.x;
    float bs = 3.5e38f; int bi = 0;
    for (int t = 0; t < 32; ++t) {
        float s = ps[(size_t)t * B + row];
        int   i = pi[(size_t)t * B + row];
        if (s < bs || (s == bs && i < bi)) { bs = s; bi = i; }
    }
    const float4* xrow = reinterpret_cast<const float4*>(x + (size_t)row * D);
    float a0 = 0.f, a1 = 0.f, a2 = 0.f, a3 = 0.f;
#pragma unroll
    for (int q = 0; q < 16; ++q) {
        float4 v = xrow[q];
        a0 = fmaf(v.x, v.x, a0); a1 = fmaf(v.y, v.y, a1);
        a2 = fmaf(v.z, v.z, a2); a3 = fmaf(v.w, v.w, a3);
    }
    float x2 = (a0 + a1) + (a2 + a3);
    float d2 = x2 + bs;
    if (d2 < 0.f) d2 = 0.f;
    out[row * 2 + 0] = (float)(bi >> 8);
    out[row * 2 + 1] = (float)(bi & 255);
    out[2 * B + row] = sqrtf(d2);
}

// ---------------------------------------------------------------------------
extern "C" void kernel_launch(void* const* d_in, const int* in_sizes, int n_in,
                              void* d_out, int out_size, void* d_ws, size_t ws_size,
                              hipStream_t stream) {
    const float* x = (const float*)d_in[0];   // [B, D]
    const float* w = (const float*)d_in[1];   // [NW, D]
    float* out = (float*)d_out;

    const size_t whi_sz = (size_t)NW * D * 2;       // 8 MB
    const size_t xhi_sz = (size_t)B * D * 2;        // 512 KB
    const size_t w2c_sz = (size_t)NW * 4;           // 256 KB
    const size_t pm_sz  = (size_t)B * NSUB * 4;     // 4 MB
    const size_t need = whi_sz + xhi_sz + w2c_sz + pm_sz;

    if (ws_size >= need) {
        char* p = (char*)d_ws;
        u16*   whi = (u16*)p;   p += whi_sz;
        u16*   xhi = (u16*)p;   p += xhi_sz;
        float* w2c = (float*)p; p += w2c_sz;
        float* pm  = (float*)p;

        k_wprep<<<NW / 256, 256, 0, stream>>>(w, whi, w2c);
        k_xprep<<<B / 256, 256, 0, stream>>>(x, xhi);
        k_screen0<<<STRIPS * (B / ROWS_BLK), 256, 0, stream>>>(whi, xhi, w2c, pm);
        k_rescore<<<B / 4, 256, 0, stream>>>(x, w, w2c, pm, out);
    } else {
        float* w2 = (float*)d_ws;
        float* ps = w2 + NW;
        int*   pi = (int*)(ps + (size_t)32 * B);
        fb_w2<<<NW / 256, 256, 0, stream>>>(w, w2);
        fb_main<<<16 * 32, 256, 0, stream>>>(x, w, w2, ps, pi);
        fb_merge<<<B / 256, 256, 0, stream>>>(x, ps, pi, out);
    }
}

// Round 7
// 115.632 us; speedup vs baseline: 2.2012x; 1.6799x over previous
//
#include <hip/hip_runtime.h>
#include <math.h>

// SOM2dLayer forward: BMU indices + quantization error.
// X[4096,64] f32, W[65536,64] f32 -> out f32: [B*2] (y,x) then [B] qe.
//
// acc'(row,n) = bf16dot(x,w) + w2c[n], w2c = -0.5*sum(w^2); s = -2*acc'.
// min_n s  <=>  max_n acc'.
//   k_wprep/k_xprep: fp32 -> bf16 copies + exact w2c
//   k_screen0: LDS-staged bf16 MFMA GEMM ->
//       pm  [row][256]  exact f32 max per 256-n coarse sub  (threshold src)
//       pmf [fine][row] round-UP bf16 max per 16-n fine sub (localization)
//   k_rescore: thr = max(pm)-MARG; qualifying coarse subs -> their fine subs
//       -> exact fp32 rescore of 16 n per qualifying fine sub; argmin with
//       first-index tie-break; qe = sqrt(max(x2+s,0)).
// Round-up bf16 in pmf is conservative (stored >= exact) -> candidate
// superset, zero false negatives. No atomics -> deterministic.

typedef short  bf16x8 __attribute__((ext_vector_type(8)));
typedef float  f32x4  __attribute__((ext_vector_type(4)));
typedef unsigned short u16;
typedef unsigned short u16x4 __attribute__((ext_vector_type(4)));

constexpr int D    = 64;
constexpr int NW   = 65536;
constexpr int B    = 4096;
constexpr int NSUB = 256;              // coarse subs/row (256 n each, scattered)
constexpr int NFINE = NW / 16;         // 4096 fine subs (16 n each)
constexpr float MARG_HALF = 0.15f;     // bf16 screen margin (acc' scale)

constexpr int STRIPS   = 16;
constexpr int STRIP_N  = NW / STRIPS;  // 4096 n per strip = 16 panels of 256
constexpr int ROWS_BLK = 128;

__device__ inline u16 bf16u(float f) {
    union { float f; unsigned u; } v; v.f = f;
    unsigned b = v.u;
    b += 0x7fffu + ((b >> 16) & 1u);   // RNE, finite inputs only
    return (u16)(b >> 16);
}

__device__ inline u16 bf16up(float f) {   // round toward +inf (conservative max)
    union { float f; unsigned u; } v; v.f = f;
    unsigned h = v.u >> 16;
    if ((v.u & 0xFFFFu) && !(v.u >> 31)) h += 1;
    return (u16)h;
}

__device__ __forceinline__ void gload_lds16(const void* g, void* l) {
    __builtin_amdgcn_global_load_lds(
        (const __attribute__((address_space(1))) unsigned int*)g,
        (__attribute__((address_space(3))) unsigned int*)l, 16, 0, 0);
}

// ---- prep: W -> bf16 + w2c ------------------------------------------------
__global__ __launch_bounds__(256) void k_wprep(const float* __restrict__ w,
                                               u16* __restrict__ whi,
                                               float* __restrict__ w2c) {
    int n = blockIdx.x * 256 + threadIdx.x;
    const float4* wr = reinterpret_cast<const float4*>(w + (size_t)n * D);
    u16* orow = whi + (size_t)n * D;
    float a0 = 0.f, a1 = 0.f, a2 = 0.f, a3 = 0.f;
#pragma unroll
    for (int h = 0; h < 8; ++h) {
        float4 v0 = wr[2 * h], v1 = wr[2 * h + 1];
        a0 = fmaf(v0.x, v0.x, a0); a1 = fmaf(v0.y, v0.y, a1);
        a2 = fmaf(v0.z, v0.z, a2); a3 = fmaf(v0.w, v0.w, a3);
        a0 = fmaf(v1.x, v1.x, a0); a1 = fmaf(v1.y, v1.y, a1);
        a2 = fmaf(v1.z, v1.z, a2); a3 = fmaf(v1.w, v1.w, a3);
        bf16x8 o = {(short)bf16u(v0.x), (short)bf16u(v0.y),
                    (short)bf16u(v0.z), (short)bf16u(v0.w),
                    (short)bf16u(v1.x), (short)bf16u(v1.y),
                    (short)bf16u(v1.z), (short)bf16u(v1.w)};
        *reinterpret_cast<bf16x8*>(orow + 8 * h) = o;
    }
    w2c[n] = -0.5f * ((a0 + a1) + (a2 + a3));
}

__global__ __launch_bounds__(256) void k_xprep(const float* __restrict__ x,
                                               u16* __restrict__ xhi) {
    int r = blockIdx.x * 256 + threadIdx.x;
    const float4* xr = reinterpret_cast<const float4*>(x + (size_t)r * D);
    u16* orow = xhi + (size_t)r * D;
#pragma unroll
    for (int h = 0; h < 8; ++h) {
        float4 v0 = xr[2 * h], v1 = xr[2 * h + 1];
        bf16x8 o = {(short)bf16u(v0.x), (short)bf16u(v0.y),
                    (short)bf16u(v0.z), (short)bf16u(v0.w),
                    (short)bf16u(v1.x), (short)bf16u(v1.y),
                    (short)bf16u(v1.z), (short)bf16u(v1.w)};
        *reinterpret_cast<bf16x8*>(orow + 8 * h) = o;
    }
}

// ---- MFMA screen: LDS-staged, double-buffered -----------------------------
// Block: 4 waves, 128 rows, sweeps one 4096-n strip (16 panels of 256 n).
// Wave wv computes n-range [wv*64, wv*64+64) of each panel.
// coarse sub = strip*16 + chunk*4 + wv (chunk = 4 panels = 256 n/wave)
// fine sub   = coarse*16 + col       (16 n: pp 0..3 x t 0..3, fixed col)
template <int WRITE_FINE>
__global__ __launch_bounds__(256, 2) void k_screen0(
        const u16* __restrict__ whi, const u16* __restrict__ xhi,
        const float* __restrict__ w2c, float* __restrict__ pm,
        u16* __restrict__ pmf) {
    __shared__ __align__(16) char smem[2][32768];
    const int bid   = blockIdx.x;
    const int strip = bid & 15;          // strip -> XCD = strip%8 (L2 colocate)
    const int rbk   = bid >> 4;
    const int tid   = threadIdx.x;
    const int wv    = tid >> 6;
    const int lane  = tid & 63;
    const int col   = lane & 15;
    const int kg    = lane >> 4;
    const int row0  = rbk * ROWS_BLK;

    bf16x8 a[8][2];
#pragma unroll
    for (int rg = 0; rg < 8; ++rg)
#pragma unroll
        for (int h = 0; h < 2; ++h)
            a[rg][h] = *reinterpret_cast<const bf16x8*>(
                xhi + (size_t)(row0 + rg * 16 + col) * D + h * 32 + kg * 8);

    const char* wbase = (const char*)whi + (size_t)strip * STRIP_N * (D * 2);
    unsigned srcoff[8];
#pragma unroll
    for (int i = 0; i < 8; ++i) {
        unsigned o = (unsigned)(i * 256 + tid) * 16;
        srcoff[i] = o ^ (((o >> 7) & 7u) << 4);
    }

    const unsigned msk = (unsigned)(col & 7) << 4;   // read-side swizzle
    const float* w2s = w2c + strip * STRIP_N;

    float mx[8][4];
#pragma unroll
    for (int rg = 0; rg < 8; ++rg)
#pragma unroll
        for (int r = 0; r < 4; ++r) mx[rg][r] = -3.4e38f;

    auto STAGE = [&](int bf, int panel) {
#pragma unroll
        for (int i = 0; i < 8; ++i)
            gload_lds16(wbase + (size_t)panel * 32768 + srcoff[i],
                        &smem[bf][i * 4096 + wv * 1024]);
    };

    STAGE(0, 0);
    __syncthreads();

    for (int p = 0; p < 16; ++p) {
        if (p < 15) STAGE((p + 1) & 1, p + 1);

        const char* buf = smem[p & 1];
        const float* w2p = w2s + p * 256;
#pragma unroll
        for (int t = 0; t < 4; ++t) {
            const int nloc = wv * 64 + t * 16 + col;
            const unsigned u0 = (unsigned)nloc * 128 + kg * 16;
            const bf16x8 b0 = *reinterpret_cast<const bf16x8*>(buf + (u0 ^ msk));
            const bf16x8 b1 = *reinterpret_cast<const bf16x8*>(buf + ((u0 + 64) ^ msk));
            const float c = w2p[nloc];
#pragma unroll
            for (int rg = 0; rg < 8; ++rg) {
                f32x4 acc = {c, c, c, c};
                acc = __builtin_amdgcn_mfma_f32_16x16x32_bf16(a[rg][0], b0, acc, 0, 0, 0);
                acc = __builtin_amdgcn_mfma_f32_16x16x32_bf16(a[rg][1], b1, acc, 0, 0, 0);
                mx[rg][0] = fmaxf(mx[rg][0], acc[0]);
                mx[rg][1] = fmaxf(mx[rg][1], acc[1]);
                mx[rg][2] = fmaxf(mx[rg][2], acc[2]);
                mx[rg][3] = fmaxf(mx[rg][3], acc[3]);
            }
        }

        if ((p & 3) == 3) {   // chunk boundary
            const int chunk = p >> 2;
            const int sub = strip * 16 + chunk * 4 + wv;

            if (WRITE_FINE) {  // per-lane fine maxes (no shuffles needed)
                const int f = sub * 16 + col;
#pragma unroll
                for (int rg = 0; rg < 8; ++rg) {
                    u16x4 h = {bf16up(mx[rg][0]), bf16up(mx[rg][1]),
                               bf16up(mx[rg][2]), bf16up(mx[rg][3])};
                    *reinterpret_cast<u16x4*>(
                        pmf + (size_t)f * B + row0 + rg * 16 + kg * 4) = h;
                }
            }

#pragma unroll
            for (int rg = 0; rg < 8; ++rg) {
                float v0 = mx[rg][0], v1 = mx[rg][1], v2 = mx[rg][2], v3 = mx[rg][3];
#pragma unroll
                for (int s = 1; s < 16; s <<= 1) {
                    v0 = fmaxf(v0, __shfl_xor(v0, s, 64));
                    v1 = fmaxf(v1, __shfl_xor(v1, s, 64));
                    v2 = fmaxf(v2, __shfl_xor(v2, s, 64));
                    v3 = fmaxf(v3, __shfl_xor(v3, s, 64));
                }
                float vv = v0;
                vv = (col == 1) ? v1 : vv;
                vv = (col == 2) ? v2 : vv;
                vv = (col == 3) ? v3 : vv;
                if (col < 4)
                    pm[(size_t)(row0 + rg * 16 + kg * 4 + col) * NSUB + sub] = vv;
                mx[rg][0] = -3.4e38f; mx[rg][1] = -3.4e38f;
                mx[rg][2] = -3.4e38f; mx[rg][3] = -3.4e38f;
            }
        }
        __syncthreads();
    }
}

// ---- exact fp32 rescore + output (one wave per row) -----------------------
template <int FINE>
__global__ __launch_bounds__(256) void k_rescore(
        const float* __restrict__ x, const float* __restrict__ w,
        const float* __restrict__ w2c, const float* __restrict__ pm,
        const u16* __restrict__ pmf, float* __restrict__ out) {
    const int wv   = threadIdx.x >> 6;
    const int lane = threadIdx.x & 63;
    const int row  = blockIdx.x * 4 + wv;

    float pv[4];
#pragma unroll
    for (int it = 0; it < 4; ++it)
        pv[it] = pm[(size_t)row * NSUB + it * 64 + lane];
    float gm = fmaxf(fmaxf(pv[0], pv[1]), fmaxf(pv[2], pv[3]));
#pragma unroll
    for (int s = 1; s < 64; s <<= 1) gm = fmaxf(gm, __shfl_xor(gm, s, 64));
    const float thr = gm - MARG_HALF;

    const float4* xr = reinterpret_cast<const float4*>(x + (size_t)row * D);
    float4 xq[16];
#pragma unroll
    for (int q = 0; q < 16; ++q) xq[q] = xr[q];

    float bestv = 3.4e38f;
    int   besti = 0x7fffffff;

#pragma unroll
    for (int it = 0; it < 4; ++it) {
        unsigned long long bm = __ballot(pv[it] >= thr);
        while (bm) {
            int sb = __ffsll(bm) - 1;
            bm &= bm - 1;
            int sub = it * 64 + sb;
            int strip = sub >> 4, chunk = (sub >> 2) & 3, wvv = sub & 3;
            int base0 = strip * 4096 + chunk * 1024 + wvv * 64;

            if (FINE) {
                // read the 16 fine bf16 (round-up) maxes of this coarse sub
                float fv = -3.4e38f;
                if (lane < 16) {
                    union { unsigned u; float f; } c;
                    c.u = (unsigned)pmf[(size_t)(sub * 16 + lane) * B + row] << 16;
                    fv = c.f;
                }
                unsigned long long fm = __ballot(fv >= thr);   // bits 0..15
                while (fm) {
                    int colq = __ffsll(fm) - 1;
                    fm &= fm - 1;
                    // 16 n of this fine sub: 16 lanes x 1 n, 4 dims-quarters
                    int j = lane & 15, q = lane >> 4;
                    int n = base0 + (j >> 2) * 256 + (j & 3) * 16 + colq;
                    const float4* wr = reinterpret_cast<const float4*>(w + (size_t)n * D);
                    float d0 = 0.f, d1 = 0.f, d2 = 0.f, d3 = 0.f;
#pragma unroll
                    for (int k = 0; k < 4; ++k) {
                        float4 wq = wr[q * 4 + k];
                        float4 xv = xq[q * 4 + k];
                        d0 = fmaf(xv.x, wq.x, d0); d1 = fmaf(xv.y, wq.y, d1);
                        d2 = fmaf(xv.z, wq.z, d2); d3 = fmaf(xv.w, wq.w, d3);
                    }
                    float d = (d0 + d1) + (d2 + d3);
                    d += __shfl_xor(d, 16, 64);
                    d += __shfl_xor(d, 32, 64);      // all 4 copies hold full dot
                    float val = -2.f * (d + w2c[n]);  // == w2 - 2*x.w exact fp32
                    if (val < bestv || (val == bestv && n < besti)) { bestv = val; besti = n; }
                }
            } else {
                int nb = base0 + lane;
#pragma unroll
                for (int q4 = 0; q4 < 4; ++q4) {
                    int n = nb + q4 * 256;
                    const float4* wr = reinterpret_cast<const float4*>(w + (size_t)n * D);
                    float d0 = 0.f, d1 = 0.f, d2 = 0.f, d3 = 0.f;
#pragma unroll
                    for (int q = 0; q < 16; ++q) {
                        float4 wq = wr[q];
                        d0 = fmaf(xq[q].x, wq.x, d0);
                        d1 = fmaf(xq[q].y, wq.y, d1);
                        d2 = fmaf(xq[q].z, wq.z, d2);
                        d3 = fmaf(xq[q].w, wq.w, d3);
                    }
                    float dot = (d0 + d1) + (d2 + d3);
                    float val = -2.f * (dot + w2c[n]);
                    if (val < bestv || (val == bestv && n < besti)) { bestv = val; besti = n; }
                }
            }
        }
    }
#pragma unroll
    for (int s = 1; s < 64; s <<= 1) {
        float ov = __shfl_xor(bestv, s, 64);
        int   oi = __shfl_xor(besti, s, 64);
        if (ov < bestv || (ov == bestv && oi < besti)) { bestv = ov; besti = oi; }
    }
    if (lane == 0) {
        float a0 = 0.f, a1 = 0.f, a2 = 0.f, a3 = 0.f;
#pragma unroll
        for (int q = 0; q < 16; ++q) {
            a0 = fmaf(xq[q].x, xq[q].x, a0);
            a1 = fmaf(xq[q].y, xq[q].y, a1);
            a2 = fmaf(xq[q].z, xq[q].z, a2);
            a3 = fmaf(xq[q].w, xq[q].w, a3);
        }
        float x2 = (a0 + a1) + (a2 + a3);
        float d2f = x2 + bestv;
        if (d2f < 0.f) d2f = 0.f;
        out[row * 2 + 0] = (float)(besti >> 8);    // bmu_y
        out[row * 2 + 1] = (float)(besti & 255);   // bmu_x
        out[2 * B + row] = sqrtf(d2f);
    }
}

// ---- fallback (round-3 proven path, ~1.3 MB ws) ---------------------------
__global__ __launch_bounds__(256) void fb_w2(const float* __restrict__ w,
                                             float* __restrict__ w2) {
    int n = blockIdx.x * 256 + threadIdx.x;
    const float4* wr = reinterpret_cast<const float4*>(w + (size_t)n * D);
    float a0 = 0.f, a1 = 0.f, a2 = 0.f, a3 = 0.f;
#pragma unroll
    for (int q = 0; q < 16; ++q) {
        float4 v = wr[q];
        a0 = fmaf(v.x, v.x, a0); a1 = fmaf(v.y, v.y, a1);
        a2 = fmaf(v.z, v.z, a2); a3 = fmaf(v.w, v.w, a3);
    }
    w2[n] = (a0 + a1) + (a2 + a3);
}

__global__ __launch_bounds__(256) void fb_main(const float* __restrict__ x,
                                               const float* __restrict__ w,
                                               const float* __restrict__ w2,
                                               float* __restrict__ ps,
                                               int* __restrict__ pi) {
    constexpr int NSTRIP = NW / 32;
    const int rb    = blockIdx.x & 15;
    const int strip = blockIdx.x >> 4;
    const int row   = rb * 256 + threadIdx.x;
    float xr[D];
    const float4* xrow = reinterpret_cast<const float4*>(x + (size_t)row * D);
#pragma unroll
    for (int q = 0; q < 16; ++q) {
        float4 v = xrow[q];
        xr[q * 4 + 0] = v.x; xr[q * 4 + 1] = v.y;
        xr[q * 4 + 2] = v.z; xr[q * 4 + 3] = v.w;
    }
    float best = 3.4e38f; int bidx = 0;
    const int n0 = strip * NSTRIP, n1 = n0 + NSTRIP;
    for (int n = n0; n < n1; ++n) {
        const float* wr = w + (size_t)n * D;
        float a0 = 0.f, a1 = 0.f, a2 = 0.f, a3 = 0.f;
#pragma unroll
        for (int d = 0; d < D; d += 4) {
            a0 = fmaf(xr[d + 0], wr[d + 0], a0);
            a1 = fmaf(xr[d + 1], wr[d + 1], a1);
            a2 = fmaf(xr[d + 2], wr[d + 2], a2);
            a3 = fmaf(xr[d + 3], wr[d + 3], a3);
        }
        float s = fmaf(-2.f, (a0 + a1) + (a2 + a3), w2[n]);
        if (s < best) { best = s; bidx = n; }
    }
    ps[(size_t)strip * B + row] = best;
    pi[(size_t)strip * B + row] = bidx;
}

__global__ __launch_bounds__(256) void fb_merge(const float* __restrict__ x,
                                                const float* __restrict__ ps,
                                                const int* __restrict__ pi,
                                                float* __restrict__ out) {
    int row = blockIdx.x * 256 + threadIdx.x;
    float bs = 3.5e38f; int bi = 0;
    for (int t = 0; t < 32; ++t) {
        float s = ps[(size_t)t * B + row];
        int   i = pi[(size_t)t * B + row];
        if (s < bs || (s == bs && i < bi)) { bs = s; bi = i; }
    }
    const float4* xrow = reinterpret_cast<const float4*>(x + (size_t)row * D);
    float a0 = 0.f, a1 = 0.f, a2 = 0.f, a3 = 0.f;
#pragma unroll
    for (int q = 0; q < 16; ++q) {
        float4 v = xrow[q];
        a0 = fmaf(v.x, v.x, a0); a1 = fmaf(v.y, v.y, a1);
        a2 = fmaf(v.z, v.z, a2); a3 = fmaf(v.w, v.w, a3);
    }
    float x2 = (a0 + a1) + (a2 + a3);
    float d2 = x2 + bs;
    if (d2 < 0.f) d2 = 0.f;
    out[row * 2 + 0] = (float)(bi >> 8);
    out[row * 2 + 1] = (float)(bi & 255);
    out[2 * B + row] = sqrtf(d2);
}

// ---------------------------------------------------------------------------
extern "C" void kernel_launch(void* const* d_in, const int* in_sizes, int n_in,
                              void* d_out, int out_size, void* d_ws, size_t ws_size,
                              hipStream_t stream) {
    const float* x = (const float*)d_in[0];   // [B, D]
    const float* w = (const float*)d_in[1];   // [NW, D]
    float* out = (float*)d_out;

    const size_t whi_sz = (size_t)NW * D * 2;        // 8 MB
    const size_t xhi_sz = (size_t)B * D * 2;         // 512 KB
    const size_t w2c_sz = (size_t)NW * 4;            // 256 KB
    const size_t pm_sz  = (size_t)B * NSUB * 4;      // 4 MB
    const size_t pmf_sz = (size_t)NFINE * B * 2;     // 33.5 MB
    const size_t need_c = whi_sz + xhi_sz + w2c_sz + pm_sz;
    const size_t need_f = need_c + pmf_sz;

    if (ws_size >= need_c) {
        char* p = (char*)d_ws;
        u16*   whi = (u16*)p;   p += whi_sz;
        u16*   xhi = (u16*)p;   p += xhi_sz;
        float* w2c = (float*)p; p += w2c_sz;
        float* pm  = (float*)p; p += pm_sz;
        u16*   pmf = (u16*)p;

        k_wprep<<<NW / 256, 256, 0, stream>>>(w, whi, w2c);
        k_xprep<<<B / 256, 256, 0, stream>>>(x, xhi);
        if (ws_size >= need_f) {
            k_screen0<1><<<STRIPS * (B / ROWS_BLK), 256, 0, stream>>>(whi, xhi, w2c, pm, pmf);
            k_rescore<1><<<B / 4, 256, 0, stream>>>(x, w, w2c, pm, pmf, out);
        } else {
            k_screen0<0><<<STRIPS * (B / ROWS_BLK), 256, 0, stream>>>(whi, xhi, w2c, pm, pmf);
            k_rescore<0><<<B / 4, 256, 0, stream>>>(x, w, w2c, pm, pmf, out);
        }
    } else {
        float* w2 = (float*)d_ws;
        float* ps = w2 + NW;
        int*   pi = (int*)(ps + (size_t)32 * B);
        fb_w2<<<NW / 256, 256, 0, stream>>>(w, w2);
        fb_main<<<16 * 32, 256, 0, stream>>>(x, w, w2, ps, pi);
        fb_merge<<<B / 256, 256, 0, stream>>>(x, ps, pi, out);
    }
}